// Round 1
// baseline (258.503 us; speedup 1.0000x reference)
//
#include <hip/hip_runtime.h>
#include <math.h>

#define B   32
#define CIN 128
#define NN  8192
#define N1  8190   // length after k=3 valid conv
#define CH  10

// K1: h2[b][o][t] = relu(b2 + W2 * relu(b1 + conv_k3(signal)))   t in [0,N1)
__global__ __launch_bounds__(256) void k1_conv12(
    const float* __restrict__ sig, const float* __restrict__ w1, const float* __restrict__ b1,
    const float* __restrict__ w2, const float* __restrict__ b2, float* __restrict__ h2out)
{
    const int t = blockIdx.x * 256 + threadIdx.x;
    const int b = blockIdx.y;
    if (t >= N1) return;

    float acc[CH];
#pragma unroll
    for (int o = 0; o < CH; ++o) acc[o] = b1[o];

    const float* sp = sig + (size_t)b * CIN * NN + t;
    for (int ci = 0; ci < CIN; ++ci) {
        const float s0 = sp[(size_t)ci * NN + 0];
        const float s1 = sp[(size_t)ci * NN + 1];
        const float s2 = sp[(size_t)ci * NN + 2];
        const float* wp = w1 + ci * 3;   // + o*CIN*3 + k
#pragma unroll
        for (int o = 0; o < CH; ++o) {
            acc[o] = fmaf(wp[o * CIN * 3 + 0], s0, acc[o]);
            acc[o] = fmaf(wp[o * CIN * 3 + 1], s1, acc[o]);
            acc[o] = fmaf(wp[o * CIN * 3 + 2], s2, acc[o]);
        }
    }

    float h1[CH];
#pragma unroll
    for (int o = 0; o < CH; ++o) h1[o] = fmaxf(acc[o], 0.f);

#pragma unroll
    for (int o = 0; o < CH; ++o) {
        float a = b2[o];
#pragma unroll
        for (int i = 0; i < CH; ++i) a = fmaf(w2[o * CH + i], h1[i], a);
        h2out[((size_t)b * CH + o) * N1 + t] = fmaxf(a, 0.f);
    }
}

// K2: h3[b,o,t] = relu(bt[o] + sum_{i,j} wt[i,o,j] * h2[b,i,t-j])  t in [0,NN)
//     left/right = sigmoid(b3 + W3 * h3)
__global__ __launch_bounds__(256) void k2_convt3(
    const float* __restrict__ h2, const float* __restrict__ wt, const float* __restrict__ bt,
    const float* __restrict__ w3, const float* __restrict__ b3, float* __restrict__ lr)
{
    const int t = blockIdx.x * 256 + threadIdx.x;
    const int b = blockIdx.y;
    if (t >= NN) return;

    float acc[CH];
#pragma unroll
    for (int o = 0; o < CH; ++o) acc[o] = bt[o];

#pragma unroll
    for (int i = 0; i < CH; ++i) {
        const float* hp = h2 + ((size_t)b * CH + i) * N1;
        const float v0 = (t < N1)               ? hp[t]     : 0.f;  // j=0
        const float v1 = (t >= 1 && t <= N1)    ? hp[t - 1] : 0.f;  // j=1
        const float v2 = (t >= 2)               ? hp[t - 2] : 0.f;  // j=2 (t-2 <= 8189 always)
        const float* wp = wt + (i * CH) * 3;
#pragma unroll
        for (int o = 0; o < CH; ++o) {
            acc[o] = fmaf(wp[o * 3 + 0], v0, acc[o]);
            acc[o] = fmaf(wp[o * 3 + 1], v1, acc[o]);
            acc[o] = fmaf(wp[o * 3 + 2], v2, acc[o]);
        }
    }

    float l = b3[0], r = b3[1];
#pragma unroll
    for (int o = 0; o < CH; ++o) {
        const float h3 = fmaxf(acc[o], 0.f);
        l = fmaf(w3[o],      h3, l);
        r = fmaf(w3[CH + o], h3, r);
    }
    l = 1.f / (1.f + expf(-l));
    r = 1.f / (1.f + expf(-r));

    lr[((size_t)b * 2 + 0) * NN + t] = l;
    lr[((size_t)b * 2 + 1) * NN + t] = r;
}

// K3: unnormalized next_diag -> out, per-block partial sums -> bsums
__global__ __launch_bounds__(256) void k3_diag(
    const float* __restrict__ lr, const float* __restrict__ cd,
    const float* __restrict__ cstp, float* __restrict__ outv, float* __restrict__ bsums)
{
    const int t = blockIdx.x * 256 + threadIdx.x;
    const int b = blockIdx.y;
    float v = 0.f;
    if (t < N1) {
        const float c0 = cd[(size_t)b * (NN - 1) + t];
        const float c1 = cd[(size_t)b * (NN - 1) + t + 1];
        const float* lp = lr + (size_t)b * 2 * NN;
        const float* rp = lp + NN;
        const float mi = c1 * rp[t + 1] + c0 * lp[t + 1];
        const float mo = rp[t] + lp[t + 2];
        v = logf(cstp[0] * mi / mo);
        outv[(size_t)b * N1 + t] = v;
    }
    __shared__ float red[256];
    red[threadIdx.x] = v;
    __syncthreads();
#pragma unroll
    for (int s = 128; s > 0; s >>= 1) {
        if (threadIdx.x < s) red[threadIdx.x] += red[threadIdx.x + s];
        __syncthreads();
    }
    if (threadIdx.x == 0) bsums[blockIdx.y * gridDim.x + blockIdx.x] = red[0];
}

// K4: reduce 1024 block sums -> mean
__global__ __launch_bounds__(256) void k4_mean(const float* __restrict__ bsums, float* __restrict__ meanp)
{
    __shared__ float red[256];
    float s = 0.f;
    for (int i = threadIdx.x; i < 1024; i += 256) s += bsums[i];
    red[threadIdx.x] = s;
    __syncthreads();
#pragma unroll
    for (int st = 128; st > 0; st >>= 1) {
        if (threadIdx.x < st) red[threadIdx.x] += red[threadIdx.x + st];
        __syncthreads();
    }
    if (threadIdx.x == 0) meanp[0] = red[0] / (float)(B * N1);
}

// K5: out -= mean
__global__ __launch_bounds__(256) void k5_sub(float* __restrict__ outv, const float* __restrict__ meanp, int n)
{
    const int i = blockIdx.x * 256 + threadIdx.x;
    if (i < n) outv[i] -= meanp[0];
}

extern "C" void kernel_launch(void* const* d_in, const int* in_sizes, int n_in,
                              void* d_out, int out_size, void* d_ws, size_t ws_size,
                              hipStream_t stream)
{
    const float* sig = (const float*)d_in[0];
    const float* cd  = (const float*)d_in[1];
    // d_in[2] = index_diag (always 1; shapes in this problem require it)
    const float* w1  = (const float*)d_in[3];
    const float* b1  = (const float*)d_in[4];
    const float* w2  = (const float*)d_in[5];
    const float* b2  = (const float*)d_in[6];
    const float* wt  = (const float*)d_in[7];
    const float* bt  = (const float*)d_in[8];
    const float* w3  = (const float*)d_in[9];
    const float* b3  = (const float*)d_in[10];
    const float* cst = (const float*)d_in[11];

    float* outv = (float*)d_out;

    // workspace layout (floats)
    float* ws   = (float*)d_ws;
    float* h2   = ws;                         // B*CH*N1   = 2,620,800
    float* lr   = h2 + (size_t)B * CH * N1;   // B*2*NN    =   524,288
    float* bsum = lr + (size_t)B * 2 * NN;    // 1024
    float* mean = bsum + 1024;                // 1

    dim3 blk(256);
    dim3 g1((N1 + 255) / 256, B);   // 32 x 32
    dim3 g2(NN / 256, B);           // 32 x 32

    k1_conv12<<<g1, blk, 0, stream>>>(sig, w1, b1, w2, b2, h2);
    k2_convt3<<<g2, blk, 0, stream>>>(h2, wt, bt, w3, b3, lr);
    k3_diag  <<<g1, blk, 0, stream>>>(lr, cd, cst, outv, bsum);
    k4_mean  <<<dim3(1), blk, 0, stream>>>(bsum, mean);
    k5_sub   <<<dim3((out_size + 255) / 256), blk, 0, stream>>>(outv, mean, out_size);
}